// Round 15
// baseline (323.937 us; speedup 1.0000x reference)
//
#include <hip/hip_runtime.h>

typedef short bf16x8 __attribute__((ext_vector_type(8)));
typedef float f32x4  __attribute__((ext_vector_type(4)));

#define N_NODES 24
#define N_EDGES 76
#define N_GRAPHS 8192
#define HID 128
#define NODE_F 16
#define EDGE_F 8
#define TOT_E (N_EDGES * N_GRAPHS)   /* 622592 */
#define ST 136     /* bf16 h-plane stride (ushorts) */
#define TT 56      /* ttT stride; k=48..55 pads explicitly zeroed */
#define AST 72     /* Ag (block-diag adjacency) stride in ushorts */
#define GPB 2      /* graphs per block */
#define M 48       /* rows per block = GPB*24 */
#define WN_OFF (5 * 16384)           /* Wn plane offset in whi/wlo */
#define W_ELEMS (5 * 16384 + 128 * 32)
#define BST 132    /* k_edgeq base stride */

// ------- static normalized adjacency (identical topology across graphs) -------
__global__ void k_pattern(const int* __restrict__ ei, unsigned short* __restrict__ Ag)
{
    __shared__ float A[N_NODES][N_NODES];
    __shared__ int cnt[N_NODES];
    __shared__ float dinv[N_NODES];
    const int t = threadIdx.x;   // 128 threads
    for (int i = t; i < N_NODES * N_NODES; i += 128) ((float*)A)[i] = 0.f;
    if (t < N_NODES) cnt[t] = 0;
    __syncthreads();
    if (t < N_EDGES) atomicAdd(&cnt[ei[TOT_E + t]], 1);   // in-degree by col
    __syncthreads();
    if (t < N_NODES) dinv[t] = rsqrtf((float)(cnt[t] + 1));  // +1 self loop
    __syncthreads();
    if (t < N_EDGES) {
        const int r = ei[t], c = ei[TOT_E + t];              // graph-0 ids are local
        atomicAdd(&A[c][r], dinv[r] * dinv[c]);              // duplicates accumulate
    }
    __syncthreads();
    if (t < N_NODES) A[t][t] += dinv[t] * dinv[t];           // self-loop term
    __syncthreads();
    for (int i = t; i < M * AST; i += 128) {
        const int row = i / AST, k = i - row * AST;
        float v = 0.f;
        if (row < N_NODES) { if (k < N_NODES) v = A[row][k]; }
        else if (k >= N_NODES && k < 2 * N_NODES) v = A[row - N_NODES][k - N_NODES];
        const unsigned int u = __float_as_uint(v);
        const unsigned short hi = (unsigned short)(u >> 16);
        const float hf = __uint_as_float(u & 0xFFFF0000u);
        const unsigned short lo = (unsigned short)(__float_as_uint(v - hf) >> 16);
        Ag[i] = hi;
        Ag[M * AST + i] = lo;
    }
}

// ------- W prep: W_conv/W_res -> [c][k] split planes; W_node -> [c][32k] padded -------
__global__ __launch_bounds__(256) void k_wprep(
    const float* __restrict__ Wcv, const float* __restrict__ Wr,
    const float* __restrict__ Wn,
    unsigned short* __restrict__ whi, unsigned short* __restrict__ wlo)
{
    int idx = blockIdx.x * 256 + threadIdx.x;    // [0, W_ELEMS)
    if (idx >= W_ELEMS) return;
    float x; int dst;
    if (idx < 5 * 16384) {
        int m = idx >> 14, rem = idx & 16383;
        int k = rem >> 7, c = rem & 127;
        const float* src = (m < 4) ? (Wcv + m * 16384) : Wr;
        x = src[k * HID + c];
        dst = m * 16384 + c * HID + k;
    } else {
        int rem = idx - 5 * 16384;
        int c = rem >> 5, k = rem & 31;
        x = (k < NODE_F) ? Wn[k * HID + c] : 0.f;
        dst = WN_OFF + c * 32 + k;
    }
    unsigned int u = __float_as_uint(x);
    unsigned short hi = (unsigned short)(u >> 16);
    float hf = __uint_as_float(u & 0xFFFF0000u);
    unsigned short lo = (unsigned short)(__float_as_uint(x - hf) >> 16);
    whi[dst] = hi;
    wlo[dst] = lo;
}

// ------- edge-term precompute: q[e] = relu(ea@We8 + We[8+j] + be) . Wd2 + bd -------
__global__ __launch_bounds__(256) void k_edgeq(
    const float* __restrict__ ea, const float* __restrict__ We,
    const float* __restrict__ be, const float* __restrict__ Wd,
    const float* __restrict__ bd, float* __restrict__ qbuf)
{
    __shared__ float base[N_EDGES * BST];   // We[8+j][c] + be[c]
    __shared__ float we8[8 * HID];
    __shared__ float wd2[HID];
    const int t = threadIdx.x;
    for (int i = t; i < N_EDGES * HID; i += 256) {
        const int j = i >> 7, c = i & 127;
        base[j * BST + c] = We[(EDGE_F + j) * HID + c] + be[c];
    }
    for (int i = t; i < 8 * HID; i += 256) we8[i] = We[i];
    if (t < HID) wd2[t] = Wd[2 * HID + t];
    __syncthreads();

    const float bd0 = bd[0];
    const int lr = t & 15, lq = (t & 63) >> 4;
    const int gw = blockIdx.x * 4 + (t >> 6);
    const int c8 = 8 * lr;
    const float4 wdA = *(const float4*)&wd2[c8];
    const float4 wdB = *(const float4*)&wd2[c8 + 4];

    for (int q = gw; q < TOT_E / 4; q += 8192) {
        const int e = q * 4 + lq;
        const int j = e % N_EDGES;
        const float4 a0 = *(const float4*)(ea + (size_t)e * EDGE_F);
        const float4 a1 = *(const float4*)(ea + (size_t)e * EDGE_F + 4);
        float4 accA = *(const float4*)&base[j * BST + c8];
        float4 accB = *(const float4*)&base[j * BST + c8 + 4];
        const float af[8] = {a0.x, a0.y, a0.z, a0.w, a1.x, a1.y, a1.z, a1.w};
#pragma unroll
        for (int f = 0; f < 8; ++f) {
            const float4 w0 = *(const float4*)&we8[f * HID + c8];
            const float4 w1 = *(const float4*)&we8[f * HID + c8 + 4];
            accA.x = fmaf(af[f], w0.x, accA.x);
            accA.y = fmaf(af[f], w0.y, accA.y);
            accA.z = fmaf(af[f], w0.z, accA.z);
            accA.w = fmaf(af[f], w0.w, accA.w);
            accB.x = fmaf(af[f], w1.x, accB.x);
            accB.y = fmaf(af[f], w1.y, accB.y);
            accB.z = fmaf(af[f], w1.z, accB.z);
            accB.w = fmaf(af[f], w1.w, accB.w);
        }
        float p = fmaxf(accA.x, 0.f) * wdA.x;
        p = fmaf(fmaxf(accA.y, 0.f), wdA.y, p);
        p = fmaf(fmaxf(accA.z, 0.f), wdA.z, p);
        p = fmaf(fmaxf(accA.w, 0.f), wdA.w, p);
        p = fmaf(fmaxf(accB.x, 0.f), wdB.x, p);
        p = fmaf(fmaxf(accB.y, 0.f), wdB.y, p);
        p = fmaf(fmaxf(accB.z, 0.f), wdB.z, p);
        p = fmaf(fmaxf(accB.w, 0.f), wdB.w, p);
#pragma unroll
        for (int o = 1; o < 16; o <<= 1) p += __shfl_xor(p, o, 64);
        if (lr == 0) qbuf[e] = p + bd0;
    }
}

__device__ __forceinline__ void split2(float xv, unsigned short& hs, unsigned short& ls)
{
    unsigned int u = __float_as_uint(xv);
    hs = (unsigned short)(u >> 16);
    float hf = __uint_as_float(u & 0xFFFF0000u);
    ls = (unsigned short)(__float_as_uint(xv - hf) >> 16);
}

// ---------------- fully fused GNN (R14 structure; Ap moved LDS -> L1-resident global) ----------------
// 512 thr = 8 waves; wave w owns 16 cols. Adjacency fragments are loaded from global
// each layer (27KB, identical across blocks -> L1-hot). Pointer is laundered per layer
// via asm so the compiler cannot hoist the loads into long-lived registers (R13 spill).
struct Smem {
    unsigned short planes[2][M * ST];       // h hi/lo (26112 B); reused as pred buffer
    unsigned short ttT[2][128 * TT + 8];    // t^T hi/lo (28704 B); x staged here first
};                                          // 54816 B -> 2 blocks/CU (register-capped anyway)

__global__ __launch_bounds__(512, 4) void k_fused(
    const float* __restrict__ x, const float* __restrict__ bn,
    const unsigned short* __restrict__ whi, const unsigned short* __restrict__ wlo,
    const unsigned short* __restrict__ Ag,
    const float* __restrict__ bcv, const float* __restrict__ br,
    const int* __restrict__ ei, const float* __restrict__ Wd,
    const float* __restrict__ qbuf, float* __restrict__ out)
{
    __shared__ Smem s;
    const int t = threadIdx.x;
    const int w = t >> 6, l = t & 63;
    const int lr = l & 15, lq = l >> 4;
    const int col16 = 16 * w + lr;
    const int hcb = 16 * w + 4 * lq;         // hcol base for transposed C/D rows
    const int wko = col16 * HID + 8 * lq;    // weight base offset (add 32*ks)

    // persistent W_res hi fragments (16 VGPR)
    bf16x8 Wrh[4];
#pragma unroll
    for (int ks = 0; ks < 4; ++ks)
        Wrh[ks] = *(const bf16x8*)(whi + 4 * 16384 + wko + 32 * ks);
    const float4 br4 = *(const float4*)(br + hcb);

    // ---- stage x split-planes ([48][32] bf16 hi/lo in ttT region) ----
    const long long n0 = (long long)blockIdx.x * M;
    {
        const float* xg = x + n0 * NODE_F;            // [48][16] fp32, 768 elems
        {
            const int e = t;
            unsigned short hs, ls;
            split2(xg[e], hs, ls);
            s.ttT[0][(e >> 4) * 32 + (e & 15)] = hs;
            s.ttT[1][(e >> 4) * 32 + (e & 15)] = ls;
        }
        if (t < 256) {
            const int e = 512 + t;
            unsigned short hs, ls;
            split2(xg[e], hs, ls);
            s.ttT[0][(e >> 4) * 32 + (e & 15)] = hs;
            s.ttT[1][(e >> 4) * 32 + (e & 15)] = ls;
        }
        // zero the x-plane k=16..31 pad: exact non-overlapping 8-ushort stores
        if (t < 192) {
            const int p = t / 96, i = t % 96;
            const int row = i >> 1, half = i & 1;
            *(uint4*)&s.ttT[p][row * 32 + 16 + 8 * half] = make_uint4(0u, 0u, 0u, 0u);
        }
    }
    __syncthreads();

    // ---- node encoder via transposed MFMA: h0^T = relu(Wn^T @ x^T + bn) -> planes ----
    {
        const bf16x8 Wnh = *(const bf16x8*)(whi + WN_OFF + col16 * 32 + 8 * lq);
        const bf16x8 Wnl = *(const bf16x8*)(wlo + WN_OFF + col16 * 32 + 8 * lq);
        const float4 bn4 = *(const float4*)(bn + hcb);
        f32x4 accE[3];
#pragma unroll
        for (int nt = 0; nt < 3; ++nt) accE[nt] = (f32x4){0.f, 0.f, 0.f, 0.f};
#pragma unroll
        for (int nt = 0; nt < 3; ++nt) {
            const bf16x8 xh = *(const bf16x8*)&s.ttT[0][(16 * nt + lr) * 32 + 8 * lq];
            const bf16x8 xl = *(const bf16x8*)&s.ttT[1][(16 * nt + lr) * 32 + 8 * lq];
            accE[nt] = __builtin_amdgcn_mfma_f32_16x16x32_bf16(Wnh, xh, accE[nt], 0, 0, 0);
            accE[nt] = __builtin_amdgcn_mfma_f32_16x16x32_bf16(Wnh, xl, accE[nt], 0, 0, 0);
            accE[nt] = __builtin_amdgcn_mfma_f32_16x16x32_bf16(Wnl, xh, accE[nt], 0, 0, 0);
        }
#pragma unroll
        for (int nt = 0; nt < 3; ++nt) {
            const int node = 16 * nt + lr;
            unsigned short hs[4], ls[4];
            const float bb[4] = {bn4.x, bn4.y, bn4.z, bn4.w};
#pragma unroll
            for (int j = 0; j < 4; ++j) {
                float v = fmaxf(accE[nt][j] + bb[j], 0.f);
                split2(v, hs[j], ls[j]);
            }
            *(ushort4*)&s.planes[0][node * ST + hcb] = make_ushort4(hs[0], hs[1], hs[2], hs[3]);
            *(ushort4*)&s.planes[1][node * ST + hcb] = make_ushort4(ls[0], ls[1], ls[2], ls[3]);
        }
    }
    __syncthreads();   // x reads done (ttT free), planes complete

    // zero ttT pad (k=48..55 per col + tail slop): keeps MFMA K-overrun reads finite
    if (t < 256) {
        *(uint4*)&s.ttT[t >> 7][(t & 127) * TT + 48] = make_uint4(0u, 0u, 0u, 0u);
    } else if (t < 258) {
        *(uint4*)&s.ttT[t - 256][128 * TT] = make_uint4(0u, 0u, 0u, 0u);
    }
    // (pad visibility across waves is guaranteed by each layer's mid barrier)

    // ---- 4 GCN layers, h resident in LDS; Ap streamed from L1 ----
    const unsigned short* agp = Ag;
    for (int lyr = 0; lyr < 4; ++lyr) {
        // launder the adjacency pointer: forbids hoisting/CSE of the per-layer Ap
        // loads into long-lived registers (which spilled to scratch in R13)
        asm volatile("" : "+s"(agp));

        bf16x8 Wch[4];
#pragma unroll
        for (int ks = 0; ks < 4; ++ks)
            Wch[ks] = *(const bf16x8*)(whi + lyr * 16384 + wko + 32 * ks);
        const float4 bc4 = *(const float4*)(bcv + lyr * HID + hcb);

        // conv (standard): accT = (h@Wc)[node][hcol]; residual (swapped): accRT = (h@Wr)^T
        f32x4 accT[3], accRT[3];
#pragma unroll
        for (int mt = 0; mt < 3; ++mt) {
            accT[mt]  = (f32x4){0.f, 0.f, 0.f, 0.f};
            accRT[mt] = (f32x4){0.f, 0.f, 0.f, 0.f};
        }
#pragma unroll
        for (int ks = 0; ks < 4; ++ks) {
            const int ko = 32 * ks + 8 * lq;
            const bf16x8 Wcl = *(const bf16x8*)(wlo + lyr * 16384 + wko + 32 * ks);
            const bf16x8 Wrl = *(const bf16x8*)(wlo + 4 * 16384 + wko + 32 * ks);
#pragma unroll
            for (int mt = 0; mt < 3; ++mt) {
                const int row16 = 16 * mt + lr;
                const bf16x8 ahi = *(const bf16x8*)&s.planes[0][row16 * ST + ko];
                const bf16x8 alo = *(const bf16x8*)&s.planes[1][row16 * ST + ko];
                accT[mt]  = __builtin_amdgcn_mfma_f32_16x16x32_bf16(ahi, Wch[ks], accT[mt], 0, 0, 0);
                accT[mt]  = __builtin_amdgcn_mfma_f32_16x16x32_bf16(alo, Wch[ks], accT[mt], 0, 0, 0);
                accT[mt]  = __builtin_amdgcn_mfma_f32_16x16x32_bf16(ahi, Wcl, accT[mt], 0, 0, 0);
                accRT[mt] = __builtin_amdgcn_mfma_f32_16x16x32_bf16(Wrh[ks], ahi, accRT[mt], 0, 0, 0);
                accRT[mt] = __builtin_amdgcn_mfma_f32_16x16x32_bf16(Wrh[ks], alo, accRT[mt], 0, 0, 0);
                accRT[mt] = __builtin_amdgcn_mfma_f32_16x16x32_bf16(Wrl, ahi, accRT[mt], 0, 0, 0);
            }
        }

        // write t^T as bf16 hi/lo: ttT[col][k], k = C/D row = 16mt+4lq+j
#pragma unroll
        for (int mt = 0; mt < 3; ++mt) {
            unsigned short hs[4], ls[4];
#pragma unroll
            for (int j = 0; j < 4; ++j) split2(accT[mt][j], hs[j], ls[j]);
            *(ushort4*)&s.ttT[0][col16 * TT + 16 * mt + 4 * lq] = make_ushort4(hs[0], hs[1], hs[2], hs[3]);
            *(ushort4*)&s.ttT[1][col16 * TT + 16 * mt + 4 * lq] = make_ushort4(ls[0], ls[1], ls[2], ls[3]);
        }
        __syncthreads();   // WAR on planes + RAW visibility of t^T/pads across waves

        // adjacency fragments from global (L1-hot after layer 0)
        bf16x8 Bh[3][2], Bl[3][2];
#pragma unroll
        for (int nt = 0; nt < 3; ++nt)
#pragma unroll
            for (int ks = 0; ks < 2; ++ks) {
                const int off = (16 * nt + lr) * AST + 32 * ks + 8 * lq;
                Bh[nt][ks] = *(const bf16x8*)(agp + off);
                Bl[nt][ks] = *(const bf16x8*)(agp + M * AST + off);
            }

        // aggregation (swapped): accF = (A@t)^T + accRT
        bf16x8 Th[2], Tl[2];
#pragma unroll
        for (int ks = 0; ks < 2; ++ks) {
            Th[ks] = *(const bf16x8*)&s.ttT[0][col16 * TT + 32 * ks + 8 * lq];
            Tl[ks] = *(const bf16x8*)&s.ttT[1][col16 * TT + 32 * ks + 8 * lq];
        }
        f32x4 accF[3];
#pragma unroll
        for (int nt = 0; nt < 3; ++nt) {
            accF[nt] = accRT[nt];
#pragma unroll
            for (int ks = 0; ks < 2; ++ks) {
                accF[nt] = __builtin_amdgcn_mfma_f32_16x16x32_bf16(Th[ks], Bh[nt][ks], accF[nt], 0, 0, 0);
                accF[nt] = __builtin_amdgcn_mfma_f32_16x16x32_bf16(Tl[ks], Bh[nt][ks], accF[nt], 0, 0, 0);
                accF[nt] = __builtin_amdgcn_mfma_f32_16x16x32_bf16(Th[ks], Bl[nt][ks], accF[nt], 0, 0, 0);
            }
        }

        const float bb[4] = {bc4.x + br4.x, bc4.y + br4.y, bc4.z + br4.z, bc4.w + br4.w};
        if (lyr < 3) {
            // bias + relu -> new h planes (b64 stores, wave-exclusive cols)
#pragma unroll
            for (int nt = 0; nt < 3; ++nt) {
                const int node = 16 * nt + lr;
                unsigned short hs[4], ls[4];
#pragma unroll
                for (int j = 0; j < 4; ++j) {
                    float v = fmaxf(accF[nt][j] + bb[j], 0.f);
                    split2(v, hs[j], ls[j]);
                }
                *(ushort4*)&s.planes[0][node * ST + hcb] = make_ushort4(hs[0], hs[1], hs[2], hs[3]);
                *(ushort4*)&s.planes[1][node * ST + hcb] = make_ushort4(ls[0], ls[1], ls[2], ls[3]);
            }
            __syncthreads();   // RAW: planes complete before next layer's conv reads
        } else {
            // ---- final layer: p0/p1 node-dots from registers -> pred in planes region ----
            // (safe: all conv plane-reads finished at this layer's mid barrier)
            float* pred = (float*)&s.planes[0][0];       // [2*48][33] padded partials
            const float4 wd0 = *(const float4*)(Wd + hcb);
            const float4 wd1 = *(const float4*)(Wd + HID + hcb);
            const int chunk = 4 * w + lq;                // 0..31
#pragma unroll
            for (int nt = 0; nt < 3; ++nt) {
                const int node = 16 * nt + lr;
                float h0 = fmaxf(accF[nt][0] + bb[0], 0.f);
                float h1 = fmaxf(accF[nt][1] + bb[1], 0.f);
                float h2 = fmaxf(accF[nt][2] + bb[2], 0.f);
                float h3 = fmaxf(accF[nt][3] + bb[3], 0.f);
                float p0 = h0 * wd0.x + h1 * wd0.y + h2 * wd0.z + h3 * wd0.w;
                float p1 = h0 * wd1.x + h1 * wd1.y + h2 * wd1.z + h3 * wd1.w;
                pred[node * 33 + chunk] = p0;
                pred[(48 + node) * 33 + chunk] = p1;
            }
            __syncthreads();
            float* pv = pred + 96 * 33;                  // [2][48] final p values
            if (t < 96) {
                const float* rowp = pred + t * 33;
                float sum = 0.f;
#pragma unroll
                for (int i = 0; i < 32; ++i) sum += rowp[i];
                pv[t] = sum;
            }
            __syncthreads();
            // decoder-lite: out[e] = p0[row] + p1[col] + q[e]
            if (t < 2 * N_EDGES) {
                const int gl = (t >= N_EDGES) ? 1 : 0;
                const int j = t - N_EDGES * gl;
                const int g = blockIdx.x * GPB + gl;
                const int e = g * N_EDGES + j;
                const int nrow = ei[e] - g * N_NODES + gl * N_NODES;          // [0,48)
                const int ncol = ei[TOT_E + e] - g * N_NODES + gl * N_NODES;  // [0,48)
                out[e] = pv[nrow] + pv[48 + ncol] + qbuf[e];
            }
        }
    }
}

extern "C" void kernel_launch(void* const* d_in, const int* in_sizes, int n_in,
                              void* d_out, int out_size, void* d_ws, size_t ws_size,
                              hipStream_t stream) {
    const float* x   = (const float*)d_in[0];
    const int*   ei  = (const int*)d_in[1];   // [2][TOT_E]
    const float* ea  = (const float*)d_in[2];
    /* d_in[3] = batch, unused */
    const float* Wn  = (const float*)d_in[4];
    const float* bn  = (const float*)d_in[5];
    const float* We  = (const float*)d_in[6];
    const float* be  = (const float*)d_in[7];
    const float* Wcv = (const float*)d_in[8];
    const float* bcv = (const float*)d_in[9];
    const float* Wr  = (const float*)d_in[10];
    const float* br  = (const float*)d_in[11];
    const float* Wd  = (const float*)d_in[12];
    const float* bd  = (const float*)d_in[13];
    float* out = (float*)d_out;

    char* ws = (char*)d_ws;
    unsigned short* whi = (unsigned short*)ws;                // W_ELEMS bf16
    unsigned short* wlo = whi + W_ELEMS;
    unsigned short* Ag  = wlo + W_ELEMS;                      // 2*48*72 bf16
    float* qbuf = (float*)(Ag + 2 * M * AST);                 // TOT_E f32

    k_pattern<<<1, 128, 0, stream>>>(ei, Ag);
    k_wprep<<<(W_ELEMS + 255) / 256, 256, 0, stream>>>(Wcv, Wr, Wn, whi, wlo);
    k_edgeq<<<2048, 256, 0, stream>>>(ea, We, be, Wd, bd, qbuf);
    k_fused<<<N_GRAPHS / GPB, 512, 0, stream>>>(x, bn, whi, wlo, Ag, bcv, br,
                                                ei, Wd, qbuf, out);
}

// Round 16
// 297.868 us; speedup vs baseline: 1.0875x; 1.0875x over previous
//
#include <hip/hip_runtime.h>

typedef short bf16x8 __attribute__((ext_vector_type(8)));
typedef float f32x4  __attribute__((ext_vector_type(4)));

#define N_NODES 24
#define N_EDGES 76
#define N_GRAPHS 8192
#define HID 128
#define NODE_F 16
#define EDGE_F 8
#define TOT_E (N_EDGES * N_GRAPHS)   /* 622592 */
#define ST 136     /* bf16 h-plane stride (ushorts) */
#define TT 56      /* ttT stride; k=48..55 pads explicitly zeroed */
#define AST 72     /* Ag (block-diag adjacency) stride in ushorts */
#define GPB 2      /* graphs per block */
#define M 48       /* rows per block = GPB*24 */
#define WN_OFF (5 * 16384)           /* Wn plane offset in whi/wlo */
#define W_ELEMS (5 * 16384 + 128 * 32)
#define BST 132    /* k_edgeq base stride */

// ------- static normalized adjacency (identical topology across graphs) -------
__global__ void k_pattern(const int* __restrict__ ei, unsigned short* __restrict__ Ag)
{
    __shared__ float A[N_NODES][N_NODES];
    __shared__ int cnt[N_NODES];
    __shared__ float dinv[N_NODES];
    const int t = threadIdx.x;   // 128 threads
    for (int i = t; i < N_NODES * N_NODES; i += 128) ((float*)A)[i] = 0.f;
    if (t < N_NODES) cnt[t] = 0;
    __syncthreads();
    if (t < N_EDGES) atomicAdd(&cnt[ei[TOT_E + t]], 1);   // in-degree by col
    __syncthreads();
    if (t < N_NODES) dinv[t] = rsqrtf((float)(cnt[t] + 1));  // +1 self loop
    __syncthreads();
    if (t < N_EDGES) {
        const int r = ei[t], c = ei[TOT_E + t];              // graph-0 ids are local
        atomicAdd(&A[c][r], dinv[r] * dinv[c]);              // duplicates accumulate
    }
    __syncthreads();
    if (t < N_NODES) A[t][t] += dinv[t] * dinv[t];           // self-loop term
    __syncthreads();
    for (int i = t; i < M * AST; i += 128) {
        const int row = i / AST, k = i - row * AST;
        float v = 0.f;
        if (row < N_NODES) { if (k < N_NODES) v = A[row][k]; }
        else if (k >= N_NODES && k < 2 * N_NODES) v = A[row - N_NODES][k - N_NODES];
        const unsigned int u = __float_as_uint(v);
        const unsigned short hi = (unsigned short)(u >> 16);
        const float hf = __uint_as_float(u & 0xFFFF0000u);
        const unsigned short lo = (unsigned short)(__float_as_uint(v - hf) >> 16);
        Ag[i] = hi;
        Ag[M * AST + i] = lo;
    }
}

// ------- W prep: W_conv/W_res -> [c][k] split planes; W_node -> [c][32k] padded -------
__global__ __launch_bounds__(256) void k_wprep(
    const float* __restrict__ Wcv, const float* __restrict__ Wr,
    const float* __restrict__ Wn,
    unsigned short* __restrict__ whi, unsigned short* __restrict__ wlo)
{
    int idx = blockIdx.x * 256 + threadIdx.x;    // [0, W_ELEMS)
    if (idx >= W_ELEMS) return;
    float x; int dst;
    if (idx < 5 * 16384) {
        int m = idx >> 14, rem = idx & 16383;
        int k = rem >> 7, c = rem & 127;
        const float* src = (m < 4) ? (Wcv + m * 16384) : Wr;
        x = src[k * HID + c];
        dst = m * 16384 + c * HID + k;
    } else {
        int rem = idx - 5 * 16384;
        int c = rem >> 5, k = rem & 31;
        x = (k < NODE_F) ? Wn[k * HID + c] : 0.f;
        dst = WN_OFF + c * 32 + k;
    }
    unsigned int u = __float_as_uint(x);
    unsigned short hi = (unsigned short)(u >> 16);
    float hf = __uint_as_float(u & 0xFFFF0000u);
    unsigned short lo = (unsigned short)(__float_as_uint(x - hf) >> 16);
    whi[dst] = hi;
    wlo[dst] = lo;
}

// ------- edge-term precompute: q[e] = relu(ea@We8 + We[8+j] + be) . Wd2 + bd -------
__global__ __launch_bounds__(256) void k_edgeq(
    const float* __restrict__ ea, const float* __restrict__ We,
    const float* __restrict__ be, const float* __restrict__ Wd,
    const float* __restrict__ bd, float* __restrict__ qbuf)
{
    __shared__ float base[N_EDGES * BST];   // We[8+j][c] + be[c]
    __shared__ float we8[8 * HID];
    __shared__ float wd2[HID];
    const int t = threadIdx.x;
    for (int i = t; i < N_EDGES * HID; i += 256) {
        const int j = i >> 7, c = i & 127;
        base[j * BST + c] = We[(EDGE_F + j) * HID + c] + be[c];
    }
    for (int i = t; i < 8 * HID; i += 256) we8[i] = We[i];
    if (t < HID) wd2[t] = Wd[2 * HID + t];
    __syncthreads();

    const float bd0 = bd[0];
    const int lr = t & 15, lq = (t & 63) >> 4;
    const int gw = blockIdx.x * 4 + (t >> 6);
    const int c8 = 8 * lr;
    const float4 wdA = *(const float4*)&wd2[c8];
    const float4 wdB = *(const float4*)&wd2[c8 + 4];

    for (int q = gw; q < TOT_E / 4; q += 8192) {
        const int e = q * 4 + lq;
        const int j = e % N_EDGES;
        const float4 a0 = *(const float4*)(ea + (size_t)e * EDGE_F);
        const float4 a1 = *(const float4*)(ea + (size_t)e * EDGE_F + 4);
        float4 accA = *(const float4*)&base[j * BST + c8];
        float4 accB = *(const float4*)&base[j * BST + c8 + 4];
        const float af[8] = {a0.x, a0.y, a0.z, a0.w, a1.x, a1.y, a1.z, a1.w};
#pragma unroll
        for (int f = 0; f < 8; ++f) {
            const float4 w0 = *(const float4*)&we8[f * HID + c8];
            const float4 w1 = *(const float4*)&we8[f * HID + c8 + 4];
            accA.x = fmaf(af[f], w0.x, accA.x);
            accA.y = fmaf(af[f], w0.y, accA.y);
            accA.z = fmaf(af[f], w0.z, accA.z);
            accA.w = fmaf(af[f], w0.w, accA.w);
            accB.x = fmaf(af[f], w1.x, accB.x);
            accB.y = fmaf(af[f], w1.y, accB.y);
            accB.z = fmaf(af[f], w1.z, accB.z);
            accB.w = fmaf(af[f], w1.w, accB.w);
        }
        float p = fmaxf(accA.x, 0.f) * wdA.x;
        p = fmaf(fmaxf(accA.y, 0.f), wdA.y, p);
        p = fmaf(fmaxf(accA.z, 0.f), wdA.z, p);
        p = fmaf(fmaxf(accA.w, 0.f), wdA.w, p);
        p = fmaf(fmaxf(accB.x, 0.f), wdB.x, p);
        p = fmaf(fmaxf(accB.y, 0.f), wdB.y, p);
        p = fmaf(fmaxf(accB.z, 0.f), wdB.z, p);
        p = fmaf(fmaxf(accB.w, 0.f), wdB.w, p);
#pragma unroll
        for (int o = 1; o < 16; o <<= 1) p += __shfl_xor(p, o, 64);
        if (lr == 0) qbuf[e] = p + bd0;
    }
}

__device__ __forceinline__ void split2(float xv, unsigned short& hs, unsigned short& ls)
{
    unsigned int u = __float_as_uint(xv);
    hs = (unsigned short)(u >> 16);
    float hf = __uint_as_float(u & 0xFFFF0000u);
    ls = (unsigned short)(__float_as_uint(xv - hf) >> 16);
}

// ---------------- fully fused GNN (R14 structure + s_setprio around MFMA bursts) ----------------
// 512 thr = 8 waves; wave w owns 16 cols. Ap staged in LDS. 2 blocks/CU run at skewed
// phases: setprio(1) during a block's MFMA bursts biases the CU scheduler toward the
// matrix pipe while the other block is staging (T5; attn-regime precedent).
struct Smem {
    unsigned short planes[2][M * ST];       // h hi/lo (26112 B); reused as pred buffer
    unsigned short ttT[2][128 * TT + 8];    // t^T hi/lo (28704 B); x staged here first
    unsigned short Ap[2][M * AST];          // block-diag A hi/lo (13824 B)
};                                          // 68640 B -> 2 blocks/CU

__global__ __launch_bounds__(512, 4) void k_fused(
    const float* __restrict__ x, const float* __restrict__ bn,
    const unsigned short* __restrict__ whi, const unsigned short* __restrict__ wlo,
    const unsigned short* __restrict__ Ag,
    const float* __restrict__ bcv, const float* __restrict__ br,
    const int* __restrict__ ei, const float* __restrict__ Wd,
    const float* __restrict__ qbuf, float* __restrict__ out)
{
    __shared__ Smem s;
    const int t = threadIdx.x;
    const int w = t >> 6, l = t & 63;
    const int lr = l & 15, lq = l >> 4;
    const int col16 = 16 * w + lr;
    const int hcb = 16 * w + 4 * lq;         // hcol base for transposed C/D rows
    const int wko = col16 * HID + 8 * lq;    // weight base offset (add 32*ks)

    // persistent W_res hi fragments (16 VGPR)
    bf16x8 Wrh[4];
#pragma unroll
    for (int ks = 0; ks < 4; ++ks)
        Wrh[ks] = *(const bf16x8*)(whi + 4 * 16384 + wko + 32 * ks);
    const float4 br4 = *(const float4*)(br + hcb);

    // ---- stage x split-planes ([48][32] bf16 hi/lo in ttT region) + Ap ----
    const long long n0 = (long long)blockIdx.x * M;
    {
        const float* xg = x + n0 * NODE_F;            // [48][16] fp32, 768 elems
        {
            const int e = t;
            unsigned short hs, ls;
            split2(xg[e], hs, ls);
            s.ttT[0][(e >> 4) * 32 + (e & 15)] = hs;
            s.ttT[1][(e >> 4) * 32 + (e & 15)] = ls;
        }
        if (t < 256) {
            const int e = 512 + t;
            unsigned short hs, ls;
            split2(xg[e], hs, ls);
            s.ttT[0][(e >> 4) * 32 + (e & 15)] = hs;
            s.ttT[1][(e >> 4) * 32 + (e & 15)] = ls;
        }
        // zero the x-plane k=16..31 pad: exact non-overlapping 8-ushort stores
        if (t < 192) {
            const int p = t / 96, i = t % 96;
            const int row = i >> 1, half = i & 1;
            *(uint4*)&s.ttT[p][row * 32 + 16 + 8 * half] = make_uint4(0u, 0u, 0u, 0u);
        }
    }
    {
        const uint4* src = (const uint4*)Ag;
        uint4* dst = (uint4*)s.Ap;
#pragma unroll 2
        for (int i = t; i < 2 * M * AST / 8; i += 512) dst[i] = src[i];
    }
    __syncthreads();

    // ---- node encoder via transposed MFMA: h0^T = relu(Wn^T @ x^T + bn) -> planes ----
    {
        const bf16x8 Wnh = *(const bf16x8*)(whi + WN_OFF + col16 * 32 + 8 * lq);
        const bf16x8 Wnl = *(const bf16x8*)(wlo + WN_OFF + col16 * 32 + 8 * lq);
        const float4 bn4 = *(const float4*)(bn + hcb);
        f32x4 accE[3];
#pragma unroll
        for (int nt = 0; nt < 3; ++nt) accE[nt] = (f32x4){0.f, 0.f, 0.f, 0.f};
        __builtin_amdgcn_s_setprio(1);
#pragma unroll
        for (int nt = 0; nt < 3; ++nt) {
            const bf16x8 xh = *(const bf16x8*)&s.ttT[0][(16 * nt + lr) * 32 + 8 * lq];
            const bf16x8 xl = *(const bf16x8*)&s.ttT[1][(16 * nt + lr) * 32 + 8 * lq];
            accE[nt] = __builtin_amdgcn_mfma_f32_16x16x32_bf16(Wnh, xh, accE[nt], 0, 0, 0);
            accE[nt] = __builtin_amdgcn_mfma_f32_16x16x32_bf16(Wnh, xl, accE[nt], 0, 0, 0);
            accE[nt] = __builtin_amdgcn_mfma_f32_16x16x32_bf16(Wnl, xh, accE[nt], 0, 0, 0);
        }
        __builtin_amdgcn_s_setprio(0);
#pragma unroll
        for (int nt = 0; nt < 3; ++nt) {
            const int node = 16 * nt + lr;
            unsigned short hs[4], ls[4];
            const float bb[4] = {bn4.x, bn4.y, bn4.z, bn4.w};
#pragma unroll
            for (int j = 0; j < 4; ++j) {
                float v = fmaxf(accE[nt][j] + bb[j], 0.f);
                split2(v, hs[j], ls[j]);
            }
            *(ushort4*)&s.planes[0][node * ST + hcb] = make_ushort4(hs[0], hs[1], hs[2], hs[3]);
            *(ushort4*)&s.planes[1][node * ST + hcb] = make_ushort4(ls[0], ls[1], ls[2], ls[3]);
        }
    }
    __syncthreads();   // x reads done (ttT free), planes complete

    // zero ttT pad (k=48..55 per col + tail slop): keeps MFMA K-overrun reads finite
    if (t < 256) {
        *(uint4*)&s.ttT[t >> 7][(t & 127) * TT + 48] = make_uint4(0u, 0u, 0u, 0u);
    } else if (t < 258) {
        *(uint4*)&s.ttT[t - 256][128 * TT] = make_uint4(0u, 0u, 0u, 0u);
    }
    // (pad visibility across waves is guaranteed by each layer's mid barrier)

    // ---- 4 GCN layers, h resident in LDS ----
    for (int lyr = 0; lyr < 4; ++lyr) {
        bf16x8 Wch[4];
#pragma unroll
        for (int ks = 0; ks < 4; ++ks)
            Wch[ks] = *(const bf16x8*)(whi + lyr * 16384 + wko + 32 * ks);
        const float4 bc4 = *(const float4*)(bcv + lyr * HID + hcb);

        // conv (standard): accT = (h@Wc)[node][hcol]; residual (swapped): accRT = (h@Wr)^T
        f32x4 accT[3], accRT[3];
#pragma unroll
        for (int mt = 0; mt < 3; ++mt) {
            accT[mt]  = (f32x4){0.f, 0.f, 0.f, 0.f};
            accRT[mt] = (f32x4){0.f, 0.f, 0.f, 0.f};
        }
        __builtin_amdgcn_s_setprio(1);
#pragma unroll
        for (int ks = 0; ks < 4; ++ks) {
            const int ko = 32 * ks + 8 * lq;
            const bf16x8 Wcl = *(const bf16x8*)(wlo + lyr * 16384 + wko + 32 * ks);
            const bf16x8 Wrl = *(const bf16x8*)(wlo + 4 * 16384 + wko + 32 * ks);
#pragma unroll
            for (int mt = 0; mt < 3; ++mt) {
                const int row16 = 16 * mt + lr;
                const bf16x8 ahi = *(const bf16x8*)&s.planes[0][row16 * ST + ko];
                const bf16x8 alo = *(const bf16x8*)&s.planes[1][row16 * ST + ko];
                accT[mt]  = __builtin_amdgcn_mfma_f32_16x16x32_bf16(ahi, Wch[ks], accT[mt], 0, 0, 0);
                accT[mt]  = __builtin_amdgcn_mfma_f32_16x16x32_bf16(alo, Wch[ks], accT[mt], 0, 0, 0);
                accT[mt]  = __builtin_amdgcn_mfma_f32_16x16x32_bf16(ahi, Wcl, accT[mt], 0, 0, 0);
                accRT[mt] = __builtin_amdgcn_mfma_f32_16x16x32_bf16(Wrh[ks], ahi, accRT[mt], 0, 0, 0);
                accRT[mt] = __builtin_amdgcn_mfma_f32_16x16x32_bf16(Wrh[ks], alo, accRT[mt], 0, 0, 0);
                accRT[mt] = __builtin_amdgcn_mfma_f32_16x16x32_bf16(Wrl, ahi, accRT[mt], 0, 0, 0);
            }
        }
        __builtin_amdgcn_s_setprio(0);

        // write t^T as bf16 hi/lo: ttT[col][k], k = C/D row = 16mt+4lq+j
#pragma unroll
        for (int mt = 0; mt < 3; ++mt) {
            unsigned short hs[4], ls[4];
#pragma unroll
            for (int j = 0; j < 4; ++j) split2(accT[mt][j], hs[j], ls[j]);
            *(ushort4*)&s.ttT[0][col16 * TT + 16 * mt + 4 * lq] = make_ushort4(hs[0], hs[1], hs[2], hs[3]);
            *(ushort4*)&s.ttT[1][col16 * TT + 16 * mt + 4 * lq] = make_ushort4(ls[0], ls[1], ls[2], ls[3]);
        }
        __syncthreads();   // WAR on planes + RAW visibility of t^T/pads across waves

        // aggregation (swapped): accF = (A@t)^T + accRT; A fragments from LDS
        bf16x8 Th[2], Tl[2];
#pragma unroll
        for (int ks = 0; ks < 2; ++ks) {
            Th[ks] = *(const bf16x8*)&s.ttT[0][col16 * TT + 32 * ks + 8 * lq];
            Tl[ks] = *(const bf16x8*)&s.ttT[1][col16 * TT + 32 * ks + 8 * lq];
        }
        f32x4 accF[3];
        __builtin_amdgcn_s_setprio(1);
#pragma unroll
        for (int nt = 0; nt < 3; ++nt) {
            const int brow = (16 * nt + lr) * AST + 8 * lq;
            accF[nt] = accRT[nt];
#pragma unroll
            for (int ks = 0; ks < 2; ++ks) {
                const bf16x8 Bh = *(const bf16x8*)&s.Ap[0][brow + 32 * ks];
                const bf16x8 Bl = *(const bf16x8*)&s.Ap[1][brow + 32 * ks];
                accF[nt] = __builtin_amdgcn_mfma_f32_16x16x32_bf16(Th[ks], Bh, accF[nt], 0, 0, 0);
                accF[nt] = __builtin_amdgcn_mfma_f32_16x16x32_bf16(Tl[ks], Bh, accF[nt], 0, 0, 0);
                accF[nt] = __builtin_amdgcn_mfma_f32_16x16x32_bf16(Th[ks], Bl, accF[nt], 0, 0, 0);
            }
        }
        __builtin_amdgcn_s_setprio(0);

        const float bb[4] = {bc4.x + br4.x, bc4.y + br4.y, bc4.z + br4.z, bc4.w + br4.w};
        if (lyr < 3) {
            // bias + relu -> new h planes (b64 stores, wave-exclusive cols)
#pragma unroll
            for (int nt = 0; nt < 3; ++nt) {
                const int node = 16 * nt + lr;
                unsigned short hs[4], ls[4];
#pragma unroll
                for (int j = 0; j < 4; ++j) {
                    float v = fmaxf(accF[nt][j] + bb[j], 0.f);
                    split2(v, hs[j], ls[j]);
                }
                *(ushort4*)&s.planes[0][node * ST + hcb] = make_ushort4(hs[0], hs[1], hs[2], hs[3]);
                *(ushort4*)&s.planes[1][node * ST + hcb] = make_ushort4(ls[0], ls[1], ls[2], ls[3]);
            }
            __syncthreads();   // RAW: planes complete before next layer's conv reads
        } else {
            // ---- final layer: p0/p1 node-dots from registers -> pred in planes region ----
            // (safe: all conv plane-reads finished at this layer's mid barrier)
            float* pred = (float*)&s.planes[0][0];       // [2*48][33] padded partials
            const float4 wd0 = *(const float4*)(Wd + hcb);
            const float4 wd1 = *(const float4*)(Wd + HID + hcb);
            const int chunk = 4 * w + lq;                // 0..31
#pragma unroll
            for (int nt = 0; nt < 3; ++nt) {
                const int node = 16 * nt + lr;
                float h0 = fmaxf(accF[nt][0] + bb[0], 0.f);
                float h1 = fmaxf(accF[nt][1] + bb[1], 0.f);
                float h2 = fmaxf(accF[nt][2] + bb[2], 0.f);
                float h3 = fmaxf(accF[nt][3] + bb[3], 0.f);
                float p0 = h0 * wd0.x + h1 * wd0.y + h2 * wd0.z + h3 * wd0.w;
                float p1 = h0 * wd1.x + h1 * wd1.y + h2 * wd1.z + h3 * wd1.w;
                pred[node * 33 + chunk] = p0;
                pred[(48 + node) * 33 + chunk] = p1;
            }
            __syncthreads();
            float* pv = pred + 96 * 33;                  // [2][48] final p values
            if (t < 96) {
                const float* rowp = pred + t * 33;
                float sum = 0.f;
#pragma unroll
                for (int i = 0; i < 32; ++i) sum += rowp[i];
                pv[t] = sum;
            }
            __syncthreads();
            // decoder-lite: out[e] = p0[row] + p1[col] + q[e]
            if (t < 2 * N_EDGES) {
                const int gl = (t >= N_EDGES) ? 1 : 0;
                const int j = t - N_EDGES * gl;
                const int g = blockIdx.x * GPB + gl;
                const int e = g * N_EDGES + j;
                const int nrow = ei[e] - g * N_NODES + gl * N_NODES;          // [0,48)
                const int ncol = ei[TOT_E + e] - g * N_NODES + gl * N_NODES;  // [0,48)
                out[e] = pv[nrow] + pv[48 + ncol] + qbuf[e];
            }
        }
    }
}

extern "C" void kernel_launch(void* const* d_in, const int* in_sizes, int n_in,
                              void* d_out, int out_size, void* d_ws, size_t ws_size,
                              hipStream_t stream) {
    const float* x   = (const float*)d_in[0];
    const int*   ei  = (const int*)d_in[1];   // [2][TOT_E]
    const float* ea  = (const float*)d_in[2];
    /* d_in[3] = batch, unused */
    const float* Wn  = (const float*)d_in[4];
    const float* bn  = (const float*)d_in[5];
    const float* We  = (const float*)d_in[6];
    const float* be  = (const float*)d_in[7];
    const float* Wcv = (const float*)d_in[8];
    const float* bcv = (const float*)d_in[9];
    const float* Wr  = (const float*)d_in[10];
    const float* br  = (const float*)d_in[11];
    const float* Wd  = (const float*)d_in[12];
    const float* bd  = (const float*)d_in[13];
    float* out = (float*)d_out;

    char* ws = (char*)d_ws;
    unsigned short* whi = (unsigned short*)ws;                // W_ELEMS bf16
    unsigned short* wlo = whi + W_ELEMS;
    unsigned short* Ag  = wlo + W_ELEMS;                      // 2*48*72 bf16
    float* qbuf = (float*)(Ag + 2 * M * AST);                 // TOT_E f32

    k_pattern<<<1, 128, 0, stream>>>(ei, Ag);
    k_wprep<<<(W_ELEMS + 255) / 256, 256, 0, stream>>>(Wcv, Wr, Wn, whi, wlo);
    k_edgeq<<<2048, 256, 0, stream>>>(ea, We, be, Wd, bd, qbuf);
    k_fused<<<N_GRAPHS / GPB, 512, 0, stream>>>(x, bn, whi, wlo, Ag, bcv, br,
                                                ei, Wd, qbuf, out);
}

// Round 17
// 272.208 us; speedup vs baseline: 1.1900x; 1.0943x over previous
//
#include <hip/hip_runtime.h>

typedef short bf16x8 __attribute__((ext_vector_type(8)));
typedef float f32x4  __attribute__((ext_vector_type(4)));

#define N_NODES 24
#define N_EDGES 76
#define N_GRAPHS 8192
#define HID 128
#define NODE_F 16
#define EDGE_F 8
#define TOT_E (N_EDGES * N_GRAPHS)   /* 622592 */
#define ST 136     /* bf16 h-plane stride (ushorts) */
#define TT 56      /* ttT stride; k=48..55 pads explicitly zeroed */
#define AST 72     /* Ag (block-diag adjacency) stride in ushorts */
#define GPB 2      /* graphs per block */
#define M 48       /* rows per block = GPB*24 */
#define WN_OFF (5 * 16384)           /* Wn plane offset in whi/wlo */
#define W_ELEMS (5 * 16384 + 128 * 32)
#define BST 132    /* k_prep edgeq base stride */

// ---- merged prep: wprep (blocks 0..335) + adjacency (block 2047) + edgeq (all) ----
// All three parts read only kernel inputs; mutually independent; feed k_fused.
__global__ __launch_bounds__(256) void k_prep(
    const int* __restrict__ ei, unsigned short* __restrict__ Ag,
    const float* __restrict__ Wcv, const float* __restrict__ Wr,
    const float* __restrict__ Wn,
    unsigned short* __restrict__ whi, unsigned short* __restrict__ wlo,
    const float* __restrict__ ea, const float* __restrict__ We,
    const float* __restrict__ be, const float* __restrict__ Wd,
    const float* __restrict__ bd, float* __restrict__ qbuf)
{
    __shared__ float base[N_EDGES * BST];   // We[8+j][c] + be[c]  (40128 B)
    __shared__ float we8[8 * HID];
    __shared__ float wd2[HID];
    __shared__ float A[N_NODES][N_NODES];   // pattern scratch (block 2047 only)
    __shared__ int cnt[N_NODES];
    __shared__ float dinv[N_NODES];
    const int t = threadIdx.x;

    // ---- part 1: W prep slice (global->global, no LDS) ----
    {
        const int idx = blockIdx.x * 256 + t;
        if (idx < W_ELEMS) {
            float x; int dst;
            if (idx < 5 * 16384) {
                int m = idx >> 14, rem = idx & 16383;
                int k = rem >> 7, c = rem & 127;
                const float* src = (m < 4) ? (Wcv + m * 16384) : Wr;
                x = src[k * HID + c];
                dst = m * 16384 + c * HID + k;
            } else {
                int rem = idx - 5 * 16384;
                int c = rem >> 5, k = rem & 31;
                x = (k < NODE_F) ? Wn[k * HID + c] : 0.f;
                dst = WN_OFF + c * 32 + k;
            }
            unsigned int u = __float_as_uint(x);
            unsigned short hi = (unsigned short)(u >> 16);
            float hf = __uint_as_float(u & 0xFFFF0000u);
            unsigned short lo = (unsigned short)(__float_as_uint(x - hf) >> 16);
            whi[dst] = hi;
            wlo[dst] = lo;
        }
    }

    // ---- part 2: static normalized adjacency (block 2047 only) ----
    if (blockIdx.x == 2047) {
        for (int i = t; i < N_NODES * N_NODES; i += 256) ((float*)A)[i] = 0.f;
        if (t < N_NODES) cnt[t] = 0;
        __syncthreads();
        if (t < N_EDGES) atomicAdd(&cnt[ei[TOT_E + t]], 1);
        __syncthreads();
        if (t < N_NODES) dinv[t] = rsqrtf((float)(cnt[t] + 1));
        __syncthreads();
        if (t < N_EDGES) {
            const int r = ei[t], c = ei[TOT_E + t];
            atomicAdd(&A[c][r], dinv[r] * dinv[c]);
        }
        __syncthreads();
        if (t < N_NODES) A[t][t] += dinv[t] * dinv[t];
        __syncthreads();
        for (int i = t; i < M * AST; i += 256) {
            const int row = i / AST, k = i - row * AST;
            float v = 0.f;
            if (row < N_NODES) { if (k < N_NODES) v = A[row][k]; }
            else if (k >= N_NODES && k < 2 * N_NODES) v = A[row - N_NODES][k - N_NODES];
            const unsigned int u = __float_as_uint(v);
            const unsigned short hi = (unsigned short)(u >> 16);
            const float hf = __uint_as_float(u & 0xFFFF0000u);
            const unsigned short lo = (unsigned short)(__float_as_uint(v - hf) >> 16);
            Ag[i] = hi;
            Ag[M * AST + i] = lo;
        }
    }

    // ---- part 3: edge-term q[e] (all blocks, grid-stride) ----
    for (int i = t; i < N_EDGES * HID; i += 256) {
        const int j = i >> 7, c = i & 127;
        base[j * BST + c] = We[(EDGE_F + j) * HID + c] + be[c];
    }
    for (int i = t; i < 8 * HID; i += 256) we8[i] = We[i];
    if (t < HID) wd2[t] = Wd[2 * HID + t];
    __syncthreads();

    const float bd0 = bd[0];
    const int lr = t & 15, lq = (t & 63) >> 4;
    const int gw = blockIdx.x * 4 + (t >> 6);
    const int c8 = 8 * lr;
    const float4 wdA = *(const float4*)&wd2[c8];
    const float4 wdB = *(const float4*)&wd2[c8 + 4];

    for (int q = gw; q < TOT_E / 4; q += 8192) {
        const int e = q * 4 + lq;
        const int j = e % N_EDGES;
        const float4 a0 = *(const float4*)(ea + (size_t)e * EDGE_F);
        const float4 a1 = *(const float4*)(ea + (size_t)e * EDGE_F + 4);
        float4 accA = *(const float4*)&base[j * BST + c8];
        float4 accB = *(const float4*)&base[j * BST + c8 + 4];
        const float af[8] = {a0.x, a0.y, a0.z, a0.w, a1.x, a1.y, a1.z, a1.w};
#pragma unroll
        for (int f = 0; f < 8; ++f) {
            const float4 w0 = *(const float4*)&we8[f * HID + c8];
            const float4 w1 = *(const float4*)&we8[f * HID + c8 + 4];
            accA.x = fmaf(af[f], w0.x, accA.x);
            accA.y = fmaf(af[f], w0.y, accA.y);
            accA.z = fmaf(af[f], w0.z, accA.z);
            accA.w = fmaf(af[f], w0.w, accA.w);
            accB.x = fmaf(af[f], w1.x, accB.x);
            accB.y = fmaf(af[f], w1.y, accB.y);
            accB.z = fmaf(af[f], w1.z, accB.z);
            accB.w = fmaf(af[f], w1.w, accB.w);
        }
        float p = fmaxf(accA.x, 0.f) * wdA.x;
        p = fmaf(fmaxf(accA.y, 0.f), wdA.y, p);
        p = fmaf(fmaxf(accA.z, 0.f), wdA.z, p);
        p = fmaf(fmaxf(accA.w, 0.f), wdA.w, p);
        p = fmaf(fmaxf(accB.x, 0.f), wdB.x, p);
        p = fmaf(fmaxf(accB.y, 0.f), wdB.y, p);
        p = fmaf(fmaxf(accB.z, 0.f), wdB.z, p);
        p = fmaf(fmaxf(accB.w, 0.f), wdB.w, p);
#pragma unroll
        for (int o = 1; o < 16; o <<= 1) p += __shfl_xor(p, o, 64);
        if (lr == 0) qbuf[e] = p + bd0;
    }
}

__device__ __forceinline__ void split2(float xv, unsigned short& hs, unsigned short& ls)
{
    unsigned int u = __float_as_uint(xv);
    hs = (unsigned short)(u >> 16);
    float hf = __uint_as_float(u & 0xFFFF0000u);
    ls = (unsigned short)(__float_as_uint(xv - hf) >> 16);
}

// ---------------- fully fused GNN (R14 best-known structure, setprio reverted) ----------------
struct Smem {
    unsigned short planes[2][M * ST];       // h hi/lo (26112 B); reused as pred buffer
    unsigned short ttT[2][128 * TT + 8];    // t^T hi/lo (28704 B); x staged here first
    unsigned short Ap[2][M * AST];          // block-diag A hi/lo (13824 B)
};                                          // 68640 B -> 2 blocks/CU

__global__ __launch_bounds__(512, 4) void k_fused(
    const float* __restrict__ x, const float* __restrict__ bn,
    const unsigned short* __restrict__ whi, const unsigned short* __restrict__ wlo,
    const unsigned short* __restrict__ Ag,
    const float* __restrict__ bcv, const float* __restrict__ br,
    const int* __restrict__ ei, const float* __restrict__ Wd,
    const float* __restrict__ qbuf, float* __restrict__ out)
{
    __shared__ Smem s;
    const int t = threadIdx.x;
    const int w = t >> 6, l = t & 63;
    const int lr = l & 15, lq = l >> 4;
    const int col16 = 16 * w + lr;
    const int hcb = 16 * w + 4 * lq;         // hcol base for transposed C/D rows
    const int wko = col16 * HID + 8 * lq;    // weight base offset (add 32*ks)

    // persistent W_res hi fragments (16 VGPR)
    bf16x8 Wrh[4];
#pragma unroll
    for (int ks = 0; ks < 4; ++ks)
        Wrh[ks] = *(const bf16x8*)(whi + 4 * 16384 + wko + 32 * ks);
    const float4 br4 = *(const float4*)(br + hcb);

    // ---- stage x split-planes ([48][32] bf16 hi/lo in ttT region) + Ap ----
    const long long n0 = (long long)blockIdx.x * M;
    {
        const float* xg = x + n0 * NODE_F;            // [48][16] fp32, 768 elems
        {
            const int e = t;
            unsigned short hs, ls;
            split2(xg[e], hs, ls);
            s.ttT[0][(e >> 4) * 32 + (e & 15)] = hs;
            s.ttT[1][(e >> 4) * 32 + (e & 15)] = ls;
        }
        if (t < 256) {
            const int e = 512 + t;
            unsigned short hs, ls;
            split2(xg[e], hs, ls);
            s.ttT[0][(e >> 4) * 32 + (e & 15)] = hs;
            s.ttT[1][(e >> 4) * 32 + (e & 15)] = ls;
        }
        // zero the x-plane k=16..31 pad: exact non-overlapping 8-ushort stores
        if (t < 192) {
            const int p = t / 96, i = t % 96;
            const int row = i >> 1, half = i & 1;
            *(uint4*)&s.ttT[p][row * 32 + 16 + 8 * half] = make_uint4(0u, 0u, 0u, 0u);
        }
    }
    {
        const uint4* src = (const uint4*)Ag;
        uint4* dst = (uint4*)s.Ap;
#pragma unroll 2
        for (int i = t; i < 2 * M * AST / 8; i += 512) dst[i] = src[i];
    }
    __syncthreads();

    // ---- node encoder via transposed MFMA: h0^T = relu(Wn^T @ x^T + bn) -> planes ----
    {
        const bf16x8 Wnh = *(const bf16x8*)(whi + WN_OFF + col16 * 32 + 8 * lq);
        const bf16x8 Wnl = *(const bf16x8*)(wlo + WN_OFF + col16 * 32 + 8 * lq);
        const float4 bn4 = *(const float4*)(bn + hcb);
        f32x4 accE[3];
#pragma unroll
        for (int nt = 0; nt < 3; ++nt) accE[nt] = (f32x4){0.f, 0.f, 0.f, 0.f};
#pragma unroll
        for (int nt = 0; nt < 3; ++nt) {
            const bf16x8 xh = *(const bf16x8*)&s.ttT[0][(16 * nt + lr) * 32 + 8 * lq];
            const bf16x8 xl = *(const bf16x8*)&s.ttT[1][(16 * nt + lr) * 32 + 8 * lq];
            accE[nt] = __builtin_amdgcn_mfma_f32_16x16x32_bf16(Wnh, xh, accE[nt], 0, 0, 0);
            accE[nt] = __builtin_amdgcn_mfma_f32_16x16x32_bf16(Wnh, xl, accE[nt], 0, 0, 0);
            accE[nt] = __builtin_amdgcn_mfma_f32_16x16x32_bf16(Wnl, xh, accE[nt], 0, 0, 0);
        }
#pragma unroll
        for (int nt = 0; nt < 3; ++nt) {
            const int node = 16 * nt + lr;
            unsigned short hs[4], ls[4];
            const float bb[4] = {bn4.x, bn4.y, bn4.z, bn4.w};
#pragma unroll
            for (int j = 0; j < 4; ++j) {
                float v = fmaxf(accE[nt][j] + bb[j], 0.f);
                split2(v, hs[j], ls[j]);
            }
            *(ushort4*)&s.planes[0][node * ST + hcb] = make_ushort4(hs[0], hs[1], hs[2], hs[3]);
            *(ushort4*)&s.planes[1][node * ST + hcb] = make_ushort4(ls[0], ls[1], ls[2], ls[3]);
        }
    }
    __syncthreads();   // x reads done (ttT free), planes complete

    // zero ttT pad (k=48..55 per col + tail slop): keeps MFMA K-overrun reads finite
    if (t < 256) {
        *(uint4*)&s.ttT[t >> 7][(t & 127) * TT + 48] = make_uint4(0u, 0u, 0u, 0u);
    } else if (t < 258) {
        *(uint4*)&s.ttT[t - 256][128 * TT] = make_uint4(0u, 0u, 0u, 0u);
    }
    // (pad visibility across waves is guaranteed by each layer's mid barrier)

    // ---- 4 GCN layers, h resident in LDS ----
    for (int lyr = 0; lyr < 4; ++lyr) {
        bf16x8 Wch[4];
#pragma unroll
        for (int ks = 0; ks < 4; ++ks)
            Wch[ks] = *(const bf16x8*)(whi + lyr * 16384 + wko + 32 * ks);
        const float4 bc4 = *(const float4*)(bcv + lyr * HID + hcb);

        // conv (standard): accT = (h@Wc)[node][hcol]; residual (swapped): accRT = (h@Wr)^T
        f32x4 accT[3], accRT[3];
#pragma unroll
        for (int mt = 0; mt < 3; ++mt) {
            accT[mt]  = (f32x4){0.f, 0.f, 0.f, 0.f};
            accRT[mt] = (f32x4){0.f, 0.f, 0.f, 0.f};
        }
#pragma unroll
        for (int ks = 0; ks < 4; ++ks) {
            const int ko = 32 * ks + 8 * lq;
            const bf16x8 Wcl = *(const bf16x8*)(wlo + lyr * 16384 + wko + 32 * ks);
            const bf16x8 Wrl = *(const bf16x8*)(wlo + 4 * 16384 + wko + 32 * ks);
#pragma unroll
            for (int mt = 0; mt < 3; ++mt) {
                const int row16 = 16 * mt + lr;
                const bf16x8 ahi = *(const bf16x8*)&s.planes[0][row16 * ST + ko];
                const bf16x8 alo = *(const bf16x8*)&s.planes[1][row16 * ST + ko];
                accT[mt]  = __builtin_amdgcn_mfma_f32_16x16x32_bf16(ahi, Wch[ks], accT[mt], 0, 0, 0);
                accT[mt]  = __builtin_amdgcn_mfma_f32_16x16x32_bf16(alo, Wch[ks], accT[mt], 0, 0, 0);
                accT[mt]  = __builtin_amdgcn_mfma_f32_16x16x32_bf16(ahi, Wcl, accT[mt], 0, 0, 0);
                accRT[mt] = __builtin_amdgcn_mfma_f32_16x16x32_bf16(Wrh[ks], ahi, accRT[mt], 0, 0, 0);
                accRT[mt] = __builtin_amdgcn_mfma_f32_16x16x32_bf16(Wrh[ks], alo, accRT[mt], 0, 0, 0);
                accRT[mt] = __builtin_amdgcn_mfma_f32_16x16x32_bf16(Wrl, ahi, accRT[mt], 0, 0, 0);
            }
        }

        // write t^T as bf16 hi/lo: ttT[col][k], k = C/D row = 16mt+4lq+j
#pragma unroll
        for (int mt = 0; mt < 3; ++mt) {
            unsigned short hs[4], ls[4];
#pragma unroll
            for (int j = 0; j < 4; ++j) split2(accT[mt][j], hs[j], ls[j]);
            *(ushort4*)&s.ttT[0][col16 * TT + 16 * mt + 4 * lq] = make_ushort4(hs[0], hs[1], hs[2], hs[3]);
            *(ushort4*)&s.ttT[1][col16 * TT + 16 * mt + 4 * lq] = make_ushort4(ls[0], ls[1], ls[2], ls[3]);
        }
        __syncthreads();   // WAR on planes + RAW visibility of t^T/pads across waves

        // aggregation (swapped): accF = (A@t)^T + accRT; A fragments from LDS
        bf16x8 Th[2], Tl[2];
#pragma unroll
        for (int ks = 0; ks < 2; ++ks) {
            Th[ks] = *(const bf16x8*)&s.ttT[0][col16 * TT + 32 * ks + 8 * lq];
            Tl[ks] = *(const bf16x8*)&s.ttT[1][col16 * TT + 32 * ks + 8 * lq];
        }
        f32x4 accF[3];
#pragma unroll
        for (int nt = 0; nt < 3; ++nt) {
            const int brow = (16 * nt + lr) * AST + 8 * lq;
            accF[nt] = accRT[nt];
#pragma unroll
            for (int ks = 0; ks < 2; ++ks) {
                const bf16x8 Bh = *(const bf16x8*)&s.Ap[0][brow + 32 * ks];
                const bf16x8 Bl = *(const bf16x8*)&s.Ap[1][brow + 32 * ks];
                accF[nt] = __builtin_amdgcn_mfma_f32_16x16x32_bf16(Th[ks], Bh, accF[nt], 0, 0, 0);
                accF[nt] = __builtin_amdgcn_mfma_f32_16x16x32_bf16(Tl[ks], Bh, accF[nt], 0, 0, 0);
                accF[nt] = __builtin_amdgcn_mfma_f32_16x16x32_bf16(Th[ks], Bl, accF[nt], 0, 0, 0);
            }
        }

        const float bb[4] = {bc4.x + br4.x, bc4.y + br4.y, bc4.z + br4.z, bc4.w + br4.w};
        if (lyr < 3) {
            // bias + relu -> new h planes (b64 stores, wave-exclusive cols)
#pragma unroll
            for (int nt = 0; nt < 3; ++nt) {
                const int node = 16 * nt + lr;
                unsigned short hs[4], ls[4];
#pragma unroll
                for (int j = 0; j < 4; ++j) {
                    float v = fmaxf(accF[nt][j] + bb[j], 0.f);
                    split2(v, hs[j], ls[j]);
                }
                *(ushort4*)&s.planes[0][node * ST + hcb] = make_ushort4(hs[0], hs[1], hs[2], hs[3]);
                *(ushort4*)&s.planes[1][node * ST + hcb] = make_ushort4(ls[0], ls[1], ls[2], ls[3]);
            }
            __syncthreads();   // RAW: planes complete before next layer's conv reads
        } else {
            // ---- final layer: p0/p1 node-dots from registers -> pred in planes region ----
            float* pred = (float*)&s.planes[0][0];       // [2*48][33] padded partials
            const float4 wd0 = *(const float4*)(Wd + hcb);
            const float4 wd1 = *(const float4*)(Wd + HID + hcb);
            const int chunk = 4 * w + lq;                // 0..31
#pragma unroll
            for (int nt = 0; nt < 3; ++nt) {
                const int node = 16 * nt + lr;
                float h0 = fmaxf(accF[nt][0] + bb[0], 0.f);
                float h1 = fmaxf(accF[nt][1] + bb[1], 0.f);
                float h2 = fmaxf(accF[nt][2] + bb[2], 0.f);
                float h3 = fmaxf(accF[nt][3] + bb[3], 0.f);
                float p0 = h0 * wd0.x + h1 * wd0.y + h2 * wd0.z + h3 * wd0.w;
                float p1 = h0 * wd1.x + h1 * wd1.y + h2 * wd1.z + h3 * wd1.w;
                pred[node * 33 + chunk] = p0;
                pred[(48 + node) * 33 + chunk] = p1;
            }
            __syncthreads();
            float* pv = pred + 96 * 33;                  // [2][48] final p values
            if (t < 96) {
                const float* rowp = pred + t * 33;
                float sum = 0.f;
#pragma unroll
                for (int i = 0; i < 32; ++i) sum += rowp[i];
                pv[t] = sum;
            }
            __syncthreads();
            // decoder-lite: out[e] = p0[row] + p1[col] + q[e]
            if (t < 2 * N_EDGES) {
                const int gl = (t >= N_EDGES) ? 1 : 0;
                const int j = t - N_EDGES * gl;
                const int g = blockIdx.x * GPB + gl;
                const int e = g * N_EDGES + j;
                const int nrow = ei[e] - g * N_NODES + gl * N_NODES;          // [0,48)
                const int ncol = ei[TOT_E + e] - g * N_NODES + gl * N_NODES;  // [0,48)
                out[e] = pv[nrow] + pv[48 + ncol] + qbuf[e];
            }
        }
    }
}

extern "C" void kernel_launch(void* const* d_in, const int* in_sizes, int n_in,
                              void* d_out, int out_size, void* d_ws, size_t ws_size,
                              hipStream_t stream) {
    const float* x   = (const float*)d_in[0];
    const int*   ei  = (const int*)d_in[1];   // [2][TOT_E]
    const float* ea  = (const float*)d_in[2];
    /* d_in[3] = batch, unused */
    const float* Wn  = (const float*)d_in[4];
    const float* bn  = (const float*)d_in[5];
    const float* We  = (const float*)d_in[6];
    const float* be  = (const float*)d_in[7];
    const float* Wcv = (const float*)d_in[8];
    const float* bcv = (const float*)d_in[9];
    const float* Wr  = (const float*)d_in[10];
    const float* br  = (const float*)d_in[11];
    const float* Wd  = (const float*)d_in[12];
    const float* bd  = (const float*)d_in[13];
    float* out = (float*)d_out;

    char* ws = (char*)d_ws;
    unsigned short* whi = (unsigned short*)ws;                // W_ELEMS bf16
    unsigned short* wlo = whi + W_ELEMS;
    unsigned short* Ag  = wlo + W_ELEMS;                      // 2*48*72 bf16
    float* qbuf = (float*)(Ag + 2 * M * AST);                 // TOT_E f32

    k_prep<<<2048, 256, 0, stream>>>(ei, Ag, Wcv, Wr, Wn, whi, wlo,
                                     ea, We, be, Wd, bd, qbuf);
    k_fused<<<N_GRAPHS / GPB, 512, 0, stream>>>(x, bn, whi, wlo, Ag, bcv, br,
                                                ei, Wd, qbuf, out);
}